// Round 3
// baseline (225.462 us; speedup 1.0000x reference)
//
#include <hip/hip_runtime.h>
#include <math.h>

#define GDIM 152
#define NA 3
#define GG (GDIM * GDIM)
#define EXP_CLAMP 1000.0f

__device__ __forceinline__ float sigmoidf(float v) {
    return 1.0f / (1.0f + __expf(-v));
}

// Each thread processes 4 consecutive gx cells (152 % 4 == 0, so no row wrap).
// Fully scalar/array-free: no scratch, no dynamic indexing. 12 float4 loads,
// 12 float4 stores per thread (6 VMEM instructions per cell).
__global__ __launch_bounds__(256) void yolo_decode_v4s(
    const float* __restrict__ x,
    const float* __restrict__ anchors,
    const int* __restrict__ img_size_p,
    float* __restrict__ out,
    int total4)  // (B * NA * G * G) / 4
{
    int tid = blockIdx.x * blockDim.x + threadIdx.x;
    if (tid >= total4) return;
    int base = tid * 4;

    float stride = (float)(*img_size_p) / (float)GDIM;  // 4.0
    float inv_s = 1.0f / stride;

    int gx0 = base % GDIM;       // multiple of 4
    int t1  = base / GDIM;
    int gy  = t1 % GDIM;
    int t2  = t1 / GDIM;         // b*NA + a
    int a   = t2 % NA;
    float gyf = (float)gy;

    // input: x[(t2*12 + c)*GG + gy*G + gx0], 16B-aligned (GG%4==0, GDIM%4==0)
    const float4* ip = (const float4*)(x + (size_t)t2 * 12 * GG + (size_t)gy * GDIM + gx0);
    const int PS = GG / 4;  // float4 plane stride

    float4 r0  = ip[0 * PS];
    float4 r1  = ip[1 * PS];
    float4 r2  = ip[2 * PS];
    float4 r3  = ip[3 * PS];
    float4 r4  = ip[4 * PS];
    float4 r5  = ip[5 * PS];
    float4 r6  = ip[6 * PS];
    float4 r7  = ip[7 * PS];
    float4 r8  = ip[8 * PS];
    float4 r9  = ip[9 * PS];
    float4 r10 = ip[10 * PS];
    float4 r11 = ip[11 * PS];

    float ah4 = anchors[a * 5 + 0] * inv_s * stride;  // anchor_h * stride
    float aw4 = anchors[a * 5 + 1] * inv_s * stride;
    float al4 = anchors[a * 5 + 2] * inv_s * stride;

    float4* op = (float4*)(out + (size_t)base * 12);  // 192 B contiguous

#define PROC(J, C)                                                        \
    do {                                                                  \
        float4 o0, o1, o2;                                                \
        o0.x = (sigmoidf(r0.C) + (float)(gx0 + J)) * stride;              \
        o0.y = (sigmoidf(r1.C) + gyf) * stride;                           \
        o0.z = sigmoidf(r2.C);                                            \
        o0.w = fminf(__expf(r3.C), EXP_CLAMP) * ah4;                      \
        o1.x = fminf(__expf(r4.C), EXP_CLAMP) * aw4;                      \
        o1.y = fminf(__expf(r5.C), EXP_CLAMP) * al4;                      \
        o1.z = r6.C;                                                      \
        o1.w = r7.C;                                                      \
        o2.x = sigmoidf(r8.C);                                            \
        o2.y = sigmoidf(r9.C);                                            \
        o2.z = sigmoidf(r10.C);                                           \
        o2.w = sigmoidf(r11.C);                                           \
        op[(J) * 3 + 0] = o0;                                             \
        op[(J) * 3 + 1] = o1;                                             \
        op[(J) * 3 + 2] = o2;                                             \
    } while (0)

    PROC(0, x);
    PROC(1, y);
    PROC(2, z);
    PROC(3, w);
#undef PROC
}

extern "C" void kernel_launch(void* const* d_in, const int* in_sizes, int n_in,
                              void* d_out, int out_size, void* d_ws, size_t ws_size,
                              hipStream_t stream) {
    const float* x        = (const float*)d_in[0];
    const float* anchors  = (const float*)d_in[1];
    const int*   img_size = (const int*)d_in[2];
    float*       out      = (float*)d_out;

    const int B = 32;
    const int total4 = (B * NA * GG) / 4;  // 554,496
    const int block = 256;
    const int grid = (total4 + block - 1) / block;  // 2166

    yolo_decode_v4s<<<grid, block, 0, stream>>>(x, anchors, img_size, out, total4);
}

// Round 4
// 189.997 us; speedup vs baseline: 1.1867x; 1.1867x over previous
//
#include <hip/hip_runtime.h>
#include <math.h>

#define GDIM 152
#define NA 3
#define GG (GDIM * GDIM)   // 23104
#define EXP_CLAMP 1000.0f
#define TILE 1024          // cells per block; 2166 * 1024 == 32*3*152*152 exactly
#define NTHREADS 256

__device__ __forceinline__ float sigmoidf(float v) {
    return 1.0f / (1.0f + __expf(-v));
}

// XOR swizzle on float4 entry index: spreads bank quads so both the
// 4-strided writes and the /3-strided reads hit all 8 bank quads evenly.
__device__ __forceinline__ int swz(int e) { return e ^ ((e >> 3) & 7); }

__global__ __launch_bounds__(NTHREADS) void yolo_decode_lds(
    const float* __restrict__ x,
    const float* __restrict__ anchors,
    const int* __restrict__ img_size_p,
    float* __restrict__ out)
{
    __shared__ float4 sh[3][TILE];   // 48 KB

    const int t = threadIdx.x;
    const int tilebase = blockIdx.x * TILE;   // global cell index of tile start

    const float stride = (float)(*img_size_p) / (float)GDIM;  // 4.0
    const float inv_s = 1.0f / stride;

    // This thread's 4 cells: cbase..cbase+3 (cbase % 4 == 0, GDIM % 4 == 0 -> same row)
    const int cbase = tilebase + 4 * t;
    const unsigned t2 = (unsigned)cbase / (unsigned)GG;  // b*NA + a (magic-mul div)
    const int pos = cbase - (int)t2 * GG;                // within-plane offset
    const int gy  = pos / GDIM;
    const int gx0 = pos - gy * GDIM;
    const int a   = (int)(t2 % 3u);
    const float gyf = (float)gy;

    // input: x[(t2*12 + ch)*GG + pos], pos % 4 == 0 -> 16B aligned
    const float4* ip = (const float4*)x + (size_t)(t2 * 12u) * (GG / 4) + (pos >> 2);
    const int PS = GG / 4;

    float4 r0  = ip[0 * PS];
    float4 r1  = ip[1 * PS];
    float4 r2  = ip[2 * PS];
    float4 r3  = ip[3 * PS];
    float4 r4  = ip[4 * PS];
    float4 r5  = ip[5 * PS];
    float4 r6  = ip[6 * PS];
    float4 r7  = ip[7 * PS];
    float4 r8  = ip[8 * PS];
    float4 r9  = ip[9 * PS];
    float4 r10 = ip[10 * PS];
    float4 r11 = ip[11 * PS];

    const float ah = anchors[a * 5 + 0] * inv_s * stride;  // anchor_h * stride
    const float aw = anchors[a * 5 + 1] * inv_s * stride;
    const float al = anchors[a * 5 + 2] * inv_s * stride;

#define PROC(J, C)                                                       \
    do {                                                                 \
        float4 o0, o1, o2;                                               \
        o0.x = (sigmoidf(r0.C) + (float)(gx0 + J)) * stride;             \
        o0.y = (sigmoidf(r1.C) + gyf) * stride;                          \
        o0.z = sigmoidf(r2.C);                                           \
        o0.w = fminf(__expf(r3.C), EXP_CLAMP) * ah;                      \
        o1.x = fminf(__expf(r4.C), EXP_CLAMP) * aw;                      \
        o1.y = fminf(__expf(r5.C), EXP_CLAMP) * al;                      \
        o1.z = r6.C;                                                     \
        o1.w = r7.C;                                                     \
        o2.x = sigmoidf(r8.C);                                           \
        o2.y = sigmoidf(r9.C);                                           \
        o2.z = sigmoidf(r10.C);                                          \
        o2.w = sigmoidf(r11.C);                                          \
        int e = swz(4 * t + (J));                                        \
        sh[0][e] = o0;                                                   \
        sh[1][e] = o1;                                                   \
        sh[2][e] = o2;                                                   \
    } while (0)

    PROC(0, x);
    PROC(1, y);
    PROC(2, z);
    PROC(3, w);
#undef PROC

    __syncthreads();

    // Phase 2: lane-contiguous stores. Tile's output = 3072 consecutive float4s.
    float4* op = (float4*)out + (size_t)tilebase * 3;
#pragma unroll
    for (int k = 0; k < 12; ++k) {
        int F = t + NTHREADS * k;                 // output float4 index in tile
        unsigned cell = (unsigned)F / 3u;         // cell within tile
        int g = F - (int)cell * 3;                // component group 0..2
        op[F] = sh[g][swz((int)cell)];
    }
}

extern "C" void kernel_launch(void* const* d_in, const int* in_sizes, int n_in,
                              void* d_out, int out_size, void* d_ws, size_t ws_size,
                              hipStream_t stream) {
    const float* x        = (const float*)d_in[0];
    const float* anchors  = (const float*)d_in[1];
    const int*   img_size = (const int*)d_in[2];
    float*       out      = (float*)d_out;

    const int B = 32;
    const int total = B * NA * GG;     // 2,217,984
    const int grid = total / TILE;     // 2166, exact

    yolo_decode_lds<<<grid, NTHREADS, 0, stream>>>(x, anchors, img_size, out);
}

// Round 6
// 189.698 us; speedup vs baseline: 1.1885x; 1.0016x over previous
//
#include <hip/hip_runtime.h>
#include <math.h>

#define GDIM 152
#define NA 3
#define GG (GDIM * GDIM)   // 23104
#define EXP_CLAMP 1000.0f
#define NTHREADS 64        // single-wave blocks: no inter-wave barrier coupling
#define TILE 256           // cells per block = 4 * NTHREADS
#define GSTRIDE (TILE + 1) // 257 float4s between group planes: quad offset 1 per group

typedef float floatx4 __attribute__((ext_vector_type(4)));  // native vec for nontemporal builtin

__device__ __forceinline__ float sigmoidf(float v) {
    return 1.0f / (1.0f + __expf(-v));
}

// XOR swizzle on float4 entry index (bijective on [0,256)): spreads bank quads
// for the 4-strided phase-1 writes.
__device__ __forceinline__ int swz(int e) { return e ^ ((e >> 3) & 7); }

__global__ __launch_bounds__(NTHREADS) void yolo_decode_w64(
    const float* __restrict__ x,
    const float* __restrict__ anchors,
    const int* __restrict__ img_size_p,
    float* __restrict__ out)
{
    __shared__ floatx4 sh[3 * GSTRIDE];   // 12,336 B

    const int t = threadIdx.x;
    const int tilebase = blockIdx.x * TILE;   // global cell index of tile start

    const float stride = (float)(*img_size_p) / (float)GDIM;  // 4.0
    const float inv_s = 1.0f / stride;

    // This thread's 4 cells: cbase..cbase+3 (cbase%4==0, GDIM%4==0, GG%4==0
    // -> same row, same plane)
    const int cbase = tilebase + 4 * t;
    const unsigned t2 = (unsigned)cbase / (unsigned)GG;  // b*NA + a
    const int pos = cbase - (int)t2 * GG;                // within-plane offset
    const int gy  = pos / GDIM;
    const int gx0 = pos - gy * GDIM;
    const int a   = (int)(t2 % 3u);
    const float gyf = (float)gy;

    const floatx4* ip = (const floatx4*)x + (size_t)(t2 * 12u) * (GG / 4) + (pos >> 2);
    const int PS = GG / 4;

    floatx4 r0  = ip[0 * PS];
    floatx4 r1  = ip[1 * PS];
    floatx4 r2  = ip[2 * PS];
    floatx4 r3  = ip[3 * PS];
    floatx4 r4  = ip[4 * PS];
    floatx4 r5  = ip[5 * PS];
    floatx4 r6  = ip[6 * PS];
    floatx4 r7  = ip[7 * PS];
    floatx4 r8  = ip[8 * PS];
    floatx4 r9  = ip[9 * PS];
    floatx4 r10 = ip[10 * PS];
    floatx4 r11 = ip[11 * PS];

    const float ah = anchors[a * 5 + 0] * inv_s * stride;  // anchor_h * stride
    const float aw = anchors[a * 5 + 1] * inv_s * stride;
    const float al = anchors[a * 5 + 2] * inv_s * stride;

#define PROC(J, C)                                                       \
    do {                                                                 \
        floatx4 o0, o1, o2;                                              \
        o0.x = (sigmoidf(r0.C) + (float)(gx0 + J)) * stride;             \
        o0.y = (sigmoidf(r1.C) + gyf) * stride;                          \
        o0.z = sigmoidf(r2.C);                                           \
        o0.w = fminf(__expf(r3.C), EXP_CLAMP) * ah;                      \
        o1.x = fminf(__expf(r4.C), EXP_CLAMP) * aw;                      \
        o1.y = fminf(__expf(r5.C), EXP_CLAMP) * al;                      \
        o1.z = r6.C;                                                     \
        o1.w = r7.C;                                                     \
        o2.x = sigmoidf(r8.C);                                           \
        o2.y = sigmoidf(r9.C);                                           \
        o2.z = sigmoidf(r10.C);                                          \
        o2.w = sigmoidf(r11.C);                                          \
        int e = swz(4 * t + (J));                                        \
        sh[0 * GSTRIDE + e] = o0;                                        \
        sh[1 * GSTRIDE + e] = o1;                                        \
        sh[2 * GSTRIDE + e] = o2;                                        \
    } while (0)

    PROC(0, x);
    PROC(1, y);
    PROC(2, z);
    PROC(3, w);
#undef PROC

    __syncthreads();   // single wave: compiles to a cheap lgkmcnt drain

    // Phase 2: lane-contiguous nontemporal stores. Tile output = 768 float4s.
    floatx4* op = (floatx4*)out + (size_t)tilebase * 3;
#pragma unroll
    for (int k = 0; k < 12; ++k) {
        int F = t + NTHREADS * k;                 // output float4 index in tile
        unsigned cell = (unsigned)F / 3u;         // cell within tile
        int g = F - (int)cell * 3;                // component group 0..2
        floatx4 v = sh[g * GSTRIDE + swz((int)cell)];
        __builtin_nontemporal_store(v, op + F);
    }
}

extern "C" void kernel_launch(void* const* d_in, const int* in_sizes, int n_in,
                              void* d_out, int out_size, void* d_ws, size_t ws_size,
                              hipStream_t stream) {
    const float* x        = (const float*)d_in[0];
    const float* anchors  = (const float*)d_in[1];
    const int*   img_size = (const int*)d_in[2];
    float*       out      = (float*)d_out;

    const int B = 32;
    const int total = B * NA * GG;     // 2,217,984
    const int grid = total / TILE;     // 8664, exact

    yolo_decode_w64<<<grid, NTHREADS, 0, stream>>>(x, anchors, img_size, out);
}